// Round 1
// baseline (1486.192 us; speedup 1.0000x reference)
//
#include <hip/hip_runtime.h>

// Fused transformer attention block on MI355X (gfx950), bf16 MFMA pipeline.
// Stages: f32->bf16 casts -> fused QKV GEMM -> GQA causal flash attention -> O GEMM (f32 out).

#define HIDDEN 4096
#define NHEADS 32
#define NKV 8
#define HD 128
#define SEQ 2048
#define BATCH 2

typedef unsigned short u16;
typedef __attribute__((ext_vector_type(8))) short bf16x8;   // 8 bf16 = 4 VGPRs (guide §3)
typedef __attribute__((ext_vector_type(4))) float f32x4;
typedef __attribute__((ext_vector_type(8))) unsigned short u16x8;

__device__ __forceinline__ u16 f2bf(float f) {
  unsigned u = __float_as_uint(f);
  return (u16)((u + 0x7fffu + ((u >> 16) & 1u)) >> 16);   // RNE
}

__device__ __forceinline__ void gload_lds16(const void* g, void* l) {
  // async global->LDS, 16B per lane; LDS dest must be wave-uniform base (HW adds lane*16)
  __builtin_amdgcn_global_load_lds((const __attribute__((address_space(1))) unsigned int*)g,
                                   (__attribute__((address_space(3))) unsigned int*)l,
                                   16, 0, 0);
}

// ---------------- cast f32 -> bf16 (optionally scaled) ----------------
__global__ __launch_bounds__(256) void cast_scale_k(const float* __restrict__ s,
                                                    u16* __restrict__ d, int n, float scale) {
  int i = (blockIdx.x * 256 + threadIdx.x) * 8;
  const int stride = gridDim.x * 256 * 8;
  for (; i < n; i += stride) {
    float4 a = *(const float4*)(s + i);
    float4 b = *(const float4*)(s + i + 4);
    u16x8 o;
    o[0] = f2bf(a.x * scale); o[1] = f2bf(a.y * scale);
    o[2] = f2bf(a.z * scale); o[3] = f2bf(a.w * scale);
    o[4] = f2bf(b.x * scale); o[5] = f2bf(b.y * scale);
    o[6] = f2bf(b.z * scale); o[7] = f2bf(b.w * scale);
    *(u16x8*)(d + i) = o;
  }
}

// ---------------- GEMM: C[m][n] = sum_k A[m][k] * B[n][k]  (B^T layout) ----------------
// 128x128 tile, BK=64, 4 waves (2x2), each wave 64x64 via 4x4 x mfma 16x16x32 bf16.
template <typename OutT>
__global__ __launch_bounds__(256) void gemm_bt_k(const u16* __restrict__ A,
                                                 const u16* __restrict__ B,
                                                 OutT* __restrict__ C,
                                                 int M, int N, int K, int ldc) {
  __shared__ __attribute__((aligned(16))) u16 As[128 * 64];
  __shared__ __attribute__((aligned(16))) u16 Bs[128 * 64];
  const int tid  = threadIdx.x;
  const int lane = tid & 63;
  const int wave = tid >> 6;
  const int wr = (wave >> 1) * 64;
  const int wc = (wave & 1) * 64;
  const int nTiles = N >> 7;
  const int m0 = (blockIdx.x / nTiles) << 7;
  const int n0 = (blockIdx.x % nTiles) << 7;
  const int rbase = lane & 15;
  const int kgrp  = (lane >> 4) << 3;

  f32x4 acc[4][4] = {};

  const int soff = tid * 16;  // byte offset of this thread's 16B within each 4KB chunk
  for (int k0 = 0; k0 < K; k0 += 64) {
#pragma unroll
    for (int c = 0; c < 4; ++c) {
      int off = c * 4096 + soff;     // byte offset in 16KB tile
      int row = off >> 7;            // tile row (128B = 64 bf16 per row)
      int ke  = (off & 127) >> 1;    // element offset within row
      gload_lds16(A + (m0 + row) * K + k0 + ke, (char*)As + c * 4096 + wave * 1024);
      gload_lds16(B + (n0 + row) * K + k0 + ke, (char*)Bs + c * 4096 + wave * 1024);
    }
    __syncthreads();
#pragma unroll
    for (int kc = 0; kc < 2; ++kc) {
      bf16x8 af[4], bfr[4];
#pragma unroll
      for (int t = 0; t < 4; ++t) {
        af[t]  = *(const bf16x8*)&As[(wr + t * 16 + rbase) * 64 + kc * 32 + kgrp];
        bfr[t] = *(const bf16x8*)&Bs[(wc + t * 16 + rbase) * 64 + kc * 32 + kgrp];
      }
#pragma unroll
      for (int i = 0; i < 4; ++i)
#pragma unroll
        for (int j = 0; j < 4; ++j)
          acc[i][j] = __builtin_amdgcn_mfma_f32_16x16x32_bf16(af[i], bfr[j], acc[i][j], 0, 0, 0);
    }
    __syncthreads();
  }

  // C/D layout: col = lane&15, row = (lane>>4)*4 + e  [m89-verified]
  const int r0 = (lane >> 4) << 2;
#pragma unroll
  for (int i = 0; i < 4; ++i)
#pragma unroll
    for (int j = 0; j < 4; ++j)
#pragma unroll
      for (int e = 0; e < 4; ++e) {
        int row = m0 + wr + i * 16 + r0 + e;
        int col = n0 + wc + j * 16 + rbase;
        if constexpr (sizeof(OutT) == 2) C[row * ldc + col] = f2bf(acc[i][j][e]);
        else                             C[row * ldc + col] = acc[i][j][e];
      }
}

// ---------------- GQA causal flash attention ----------------
// grid: B*H*(S/64) blocks, 256 threads (4 waves x 16 q-rows). Q scale pre-folded into Wq.
// qkv layout: [B*S][6144]; Q at col h*128, K at 4096+kh*128, V at 5120+kh*128.
__global__ __launch_bounds__(256) void attn_k(const u16* __restrict__ qkv,
                                              u16* __restrict__ out) {
  // LDS carve-up (bytes): Qs[64][136]@0, Ks[64][136]@17408, Vt[128][72]@34816, Ps[4][16][72]@53248
  __shared__ __attribute__((aligned(16))) u16 smem[31232];
  u16* Qs = smem;             // padded +8 -> 2-way banks only
  u16* Ks = smem + 8704;
  u16* Vt = smem + 17408;     // V transposed: Vt[d][kv]
  u16* Ps = smem + 26624;     // per-wave P patch [16][72]

  const int bid = blockIdx.x;
  const int qt = bid & 31;
  const int h  = (bid >> 5) & 31;
  const int b  = bid >> 10;
  const int kh = h >> 2;                 // repeat_interleave(4)
  const int q0 = qt << 6;
  const int tid  = threadIdx.x;
  const int lane = tid & 63;
  const int w = tid >> 6;
  const int rbase = lane & 15;
  const int kgrp  = (lane >> 4) << 3;
  const int ldq = 6144;
  const u16* qbase = qkv + (b * SEQ) * ldq;

  // stage Q tile [64][128] -> LDS (padded rows)
#pragma unroll
  for (int c = 0; c < 4; ++c) {
    int off = c * 2048 + tid * 8;
    int r = off >> 7, d = off & 127;
    u16x8 v = *(const u16x8*)(qbase + (q0 + r) * ldq + h * HD + d);
    *(u16x8*)(Qs + r * 136 + d) = v;
  }
  __syncthreads();

  // Q fragments in registers: A[m=lane&15][k-chunk]
  bf16x8 aq[4];
#pragma unroll
  for (int kc = 0; kc < 4; ++kc)
    aq[kc] = *(const bf16x8*)&Qs[(w * 16 + rbase) * 136 + kc * 32 + kgrp];

  float m_r[4], l_r[4];
  f32x4 acco[8] = {};
#pragma unroll
  for (int i = 0; i < 4; ++i) { m_r[i] = -1e30f; l_r[i] = 0.f; }

  for (int kt = 0; kt <= qt; ++kt) {
    const int kv0 = kt << 6;
    // stage K (padded) and V (transposed)
#pragma unroll
    for (int c = 0; c < 4; ++c) {
      int off = c * 2048 + tid * 8;
      int r = off >> 7, d = off & 127;
      u16x8 kvv = *(const u16x8*)(qbase + (kv0 + r) * ldq + 4096 + kh * HD + d);
      *(u16x8*)(Ks + r * 136 + d) = kvv;
      u16x8 vv = *(const u16x8*)(qbase + (kv0 + r) * ldq + 5120 + kh * HD + d);
#pragma unroll
      for (int j = 0; j < 8; ++j) Vt[(d + j) * 72 + r] = vv[j];
    }
    __syncthreads();

    // S = Q K^T  (64 q-rows x 64 kv-cols per block; this wave: 16 x 64)
    f32x4 accs[4] = {};
#pragma unroll
    for (int nt = 0; nt < 4; ++nt) {
#pragma unroll
      for (int kc = 0; kc < 4; ++kc) {
        bf16x8 bk = *(const bf16x8*)&Ks[(nt * 16 + rbase) * 136 + kc * 32 + kgrp];
        accs[nt] = __builtin_amdgcn_mfma_f32_16x16x32_bf16(aq[kc], bk, accs[nt], 0, 0, 0);
      }
    }
    // causal mask: only the diagonal tile needs it
    if (kt == qt) {
#pragma unroll
      for (int nt = 0; nt < 4; ++nt)
#pragma unroll
        for (int i = 0; i < 4; ++i) {
          int row = q0 + w * 16 + ((lane >> 4) << 2) + i;
          int col = kv0 + nt * 16 + rbase;
          if (col > row) accs[nt][i] = -1e30f;
        }
    }
    // online softmax (row lives across the 16 lanes sharing lane>>4)
    float nm[4], al[4], rs[4];
#pragma unroll
    for (int i = 0; i < 4; ++i) {
      float mx = fmaxf(fmaxf(accs[0][i], accs[1][i]), fmaxf(accs[2][i], accs[3][i]));
      mx = fmaxf(mx, __shfl_xor(mx, 1));
      mx = fmaxf(mx, __shfl_xor(mx, 2));
      mx = fmaxf(mx, __shfl_xor(mx, 4));
      mx = fmaxf(mx, __shfl_xor(mx, 8));
      nm[i] = fmaxf(m_r[i], mx);
      al[i] = __expf(m_r[i] - nm[i]);
      m_r[i] = nm[i];
      rs[i] = 0.f;
    }
    // P = exp(S - m), write to per-wave LDS patch (C-layout -> A-frag layout)
    u16* Pw = Ps + w * 1152;
#pragma unroll
    for (int nt = 0; nt < 4; ++nt)
#pragma unroll
      for (int i = 0; i < 4; ++i) {
        float p = __expf(accs[nt][i] - nm[i]);
        rs[i] += p;
        Pw[(((lane >> 4) << 2) + i) * 72 + nt * 16 + rbase] = f2bf(p);
      }
#pragma unroll
    for (int i = 0; i < 4; ++i) {
      float s = rs[i];
      s += __shfl_xor(s, 1); s += __shfl_xor(s, 2);
      s += __shfl_xor(s, 4); s += __shfl_xor(s, 8);
      l_r[i] = l_r[i] * al[i] + s;
    }
    // rescale O
#pragma unroll
    for (int n = 0; n < 8; ++n)
#pragma unroll
      for (int i = 0; i < 4; ++i) acco[n][i] *= al[i];
    // O += P V   (Vt gives contiguous B-fragments)
    bf16x8 ap[2];
#pragma unroll
    for (int kc = 0; kc < 2; ++kc)
      ap[kc] = *(const bf16x8*)&Pw[rbase * 72 + kc * 32 + kgrp];
#pragma unroll
    for (int n = 0; n < 8; ++n) {
#pragma unroll
      for (int kc = 0; kc < 2; ++kc) {
        bf16x8 bv = *(const bf16x8*)&Vt[(n * 16 + rbase) * 72 + kc * 32 + kgrp];
        acco[n] = __builtin_amdgcn_mfma_f32_16x16x32_bf16(ap[kc], bv, acco[n], 0, 0, 0);
      }
    }
    __syncthreads();
  }

  // epilogue: O /= l, write bf16 [B*S][4096]
#pragma unroll
  for (int i = 0; i < 4; ++i) l_r[i] = 1.0f / l_r[i];
  const int orow0 = b * SEQ + q0 + w * 16 + ((lane >> 4) << 2);
#pragma unroll
  for (int n = 0; n < 8; ++n)
#pragma unroll
    for (int i = 0; i < 4; ++i)
      out[(orow0 + i) * HIDDEN + h * HD + n * 16 + rbase] = f2bf(acco[n][i] * l_r[i]);
}

// ---------------- launcher ----------------
extern "C" void kernel_launch(void* const* d_in, const int* in_sizes, int n_in,
                              void* d_out, int out_size, void* d_ws, size_t ws_size,
                              hipStream_t stream) {
  (void)in_sizes; (void)n_in; (void)out_size; (void)ws_size;
  const float* x  = (const float*)d_in[0];
  const float* Wq = (const float*)d_in[1];
  const float* Wk = (const float*)d_in[2];
  const float* Wv = (const float*)d_in[3];
  const float* Wo = (const float*)d_in[4];
  float* out = (float*)d_out;

  char* ws = (char*)d_ws;
  u16* xb   = (u16*)(ws);                  // [4096][4096]   33.5 MB
  u16* wqkv = (u16*)(ws + 33554432);       // [6144][4096]   50.3 MB (Wq|Wk|Wv rows)
  u16* wo   = (u16*)(ws + 83886080);       // [4096][4096]   33.5 MB
  u16* qkv  = (u16*)(ws + 117440512);      // [4096][6144]   50.3 MB
  u16* attn = (u16*)(ws + 167772160);      // [4096][4096]   33.5 MB

  const float qscale = 0.08838834764831845f;  // 1/sqrt(128), folded into Wq

  cast_scale_k<<<2048, 256, 0, stream>>>(x,  xb,   16777216, 1.0f);
  cast_scale_k<<<2048, 256, 0, stream>>>(Wq, wqkv, 16777216, qscale);
  cast_scale_k<<<1024, 256, 0, stream>>>(Wk, wqkv + 16777216, 4194304, 1.0f);
  cast_scale_k<<<1024, 256, 0, stream>>>(Wv, wqkv + 20971520, 4194304, 1.0f);
  cast_scale_k<<<2048, 256, 0, stream>>>(Wo, wo,   16777216, 1.0f);

  // fused QKV projection: [4096,4096] x [6144,4096]^T -> [4096][6144] bf16
  gemm_bt_k<u16><<<32 * 48, 256, 0, stream>>>(xb, wqkv, qkv, 4096, 6144, 4096, 6144);

  // attention: B*H*(S/64) = 2*32*32 blocks
  attn_k<<<2048, 256, 0, stream>>>(qkv, attn);

  // O projection -> f32 output
  gemm_bt_k<float><<<32 * 32, 256, 0, stream>>>(attn, wo, out, 4096, 4096, 4096, 4096);
}

// Round 2
// 1013.152 us; speedup vs baseline: 1.4669x; 1.4669x over previous
//
#include <hip/hip_runtime.h>

// Fused transformer attention block on MI355X (gfx950), bf16 MFMA pipeline.
// Stages: f32->bf16 casts -> fused QKV GEMM -> V transpose -> GQA causal flash attention -> O GEMM.

#define HIDDEN 4096
#define NHEADS 32
#define NKV 8
#define HD 128
#define SEQ 2048
#define BATCH 2

typedef unsigned short u16;
typedef __attribute__((ext_vector_type(8))) short bf16x8;   // 8 bf16 = 4 VGPRs
typedef __attribute__((ext_vector_type(4))) float f32x4;
typedef __attribute__((ext_vector_type(8))) unsigned short u16x8;

__device__ __forceinline__ u16 f2bf(float f) {
  unsigned u = __float_as_uint(f);
  return (u16)((u + 0x7fffu + ((u >> 16) & 1u)) >> 16);   // RNE
}

__device__ __forceinline__ void gload_lds16(const void* g, void* l) {
  __builtin_amdgcn_global_load_lds((const __attribute__((address_space(1))) unsigned int*)g,
                                   (__attribute__((address_space(3))) unsigned int*)l,
                                   16, 0, 0);
}

// ---------------- cast f32 -> bf16 (optionally scaled) ----------------
__global__ __launch_bounds__(256) void cast_scale_k(const float* __restrict__ s,
                                                    u16* __restrict__ d, int n, float scale) {
  int i = (blockIdx.x * 256 + threadIdx.x) * 8;
  const int stride = gridDim.x * 256 * 8;
  for (; i < n; i += stride) {
    float4 a = *(const float4*)(s + i);
    float4 b = *(const float4*)(s + i + 4);
    u16x8 o;
    o[0] = f2bf(a.x * scale); o[1] = f2bf(a.y * scale);
    o[2] = f2bf(a.z * scale); o[3] = f2bf(a.w * scale);
    o[4] = f2bf(b.x * scale); o[5] = f2bf(b.y * scale);
    o[6] = f2bf(b.z * scale); o[7] = f2bf(b.w * scale);
    *(u16x8*)(d + i) = o;
  }
}

// ---------------- V transpose: vt[c][token] = qkv[token][5120+c] ----------------
// c in [0,1024) (= kh*128+d), token in [0,4096). 64x64 tiles, LDS-staged.
__global__ __launch_bounds__(256) void transpose_v_k(const u16* __restrict__ qkv,
                                                     u16* __restrict__ vt) {
  __shared__ __attribute__((aligned(16))) u16 T[64 * 72];
  const int c0 = (blockIdx.x & 15) << 6;
  const int r0 = (blockIdx.x >> 4) << 6;
  const int tid = threadIdx.x;
#pragma unroll
  for (int p = 0; p < 2; ++p) {
    int off = p * 2048 + tid * 8;
    int tr = off >> 6, tc = off & 63;
    u16x8 v = *(const u16x8*)(qkv + (size_t)(r0 + tr) * 6144 + 5120 + c0 + tc);
#pragma unroll
    for (int j = 0; j < 8; ++j) T[(tc + j) * 72 + tr] = v[j];
  }
  __syncthreads();
#pragma unroll
  for (int p = 0; p < 2; ++p) {
    int off = p * 2048 + tid * 8;
    int oc = off >> 6, orr = off & 63;
    u16x8 v = *(const u16x8*)(T + oc * 72 + orr);
    *(u16x8*)(vt + (size_t)(c0 + oc) * 4096 + r0 + orr) = v;
  }
}

// ---------------- GEMM: C[m][n] = sum_k A[m][k] * B[n][k]  (B^T layout) ----------------
// 128x128 tile, BK=64, 4 waves (2x2), each wave 64x64 via 4x4 x mfma 16x16x32 bf16.
template <typename OutT>
__global__ __launch_bounds__(256) void gemm_bt_k(const u16* __restrict__ A,
                                                 const u16* __restrict__ B,
                                                 OutT* __restrict__ C,
                                                 int M, int N, int K, int ldc) {
  __shared__ __attribute__((aligned(16))) u16 As[128 * 64];
  __shared__ __attribute__((aligned(16))) u16 Bs[128 * 64];
  const int tid  = threadIdx.x;
  const int lane = tid & 63;
  const int wave = tid >> 6;
  const int wr = (wave >> 1) * 64;
  const int wc = (wave & 1) * 64;
  const int nTiles = N >> 7;
  // bijective XCD swizzle (grid is always a multiple of 8 here)
  const int nwg = gridDim.x;
  const int bswz = (blockIdx.x & 7) * (nwg >> 3) + (blockIdx.x >> 3);
  const int m0 = (bswz / nTiles) << 7;
  const int n0 = (bswz % nTiles) << 7;
  const int rbase = lane & 15;
  const int kgrp  = (lane >> 4) << 3;

  f32x4 acc[4][4] = {};

  const int soff = tid * 16;  // byte offset of this thread's 16B within each 4KB chunk
  for (int k0 = 0; k0 < K; k0 += 64) {
#pragma unroll
    for (int c = 0; c < 4; ++c) {
      int off = c * 4096 + soff;     // byte offset in 16KB tile
      int row = off >> 7;            // tile row (128B = 64 bf16 per row)
      int ke  = (off & 127) >> 1;    // element offset within row
      gload_lds16(A + (size_t)(m0 + row) * K + k0 + ke, (char*)As + c * 4096 + wave * 1024);
      gload_lds16(B + (size_t)(n0 + row) * K + k0 + ke, (char*)Bs + c * 4096 + wave * 1024);
    }
    __syncthreads();
#pragma unroll
    for (int kc = 0; kc < 2; ++kc) {
      bf16x8 af[4], bfr[4];
#pragma unroll
      for (int t = 0; t < 4; ++t) {
        af[t]  = *(const bf16x8*)&As[(wr + t * 16 + rbase) * 64 + kc * 32 + kgrp];
        bfr[t] = *(const bf16x8*)&Bs[(wc + t * 16 + rbase) * 64 + kc * 32 + kgrp];
      }
#pragma unroll
      for (int i = 0; i < 4; ++i)
#pragma unroll
        for (int j = 0; j < 4; ++j)
          acc[i][j] = __builtin_amdgcn_mfma_f32_16x16x32_bf16(af[i], bfr[j], acc[i][j], 0, 0, 0);
    }
    __syncthreads();
  }

  // C/D layout: col = lane&15, row = (lane>>4)*4 + e  [m89-verified]
  const int r0 = (lane >> 4) << 2;
#pragma unroll
  for (int i = 0; i < 4; ++i)
#pragma unroll
    for (int j = 0; j < 4; ++j)
#pragma unroll
      for (int e = 0; e < 4; ++e) {
        int row = m0 + wr + i * 16 + r0 + e;
        int col = n0 + wc + j * 16 + rbase;
        if constexpr (sizeof(OutT) == 2) C[(size_t)row * ldc + col] = f2bf(acc[i][j][e]);
        else                             C[(size_t)row * ldc + col] = acc[i][j][e];
      }
}

// ---------------- GQA causal flash attention ----------------
// grid: B*H*(S/128) = 1024 blocks, 512 threads (8 waves x 16 q-rows each).
// qkv layout: [B*S][6144]; Q at col h*128, K at 4096+kh*128. V comes pre-transposed from vt.
__global__ __launch_bounds__(512) void attn_k(const u16* __restrict__ qkv,
                                              const u16* __restrict__ vt,
                                              u16* __restrict__ out) {
  __shared__ __attribute__((aligned(16))) u16 smem[27136];   // 54.3 KB
  u16* Ks = smem;            // [64][136] padded
  u16* Vt = smem + 8704;     // [128][72] padded (Vt[d][kv])
  u16* Ps = smem + 17920;    // [8 waves][16][72]

  const int bid = blockIdx.x;
  const int qt = bid & 15;
  const int h  = (bid >> 4) & 31;
  const int b  = bid >> 9;
  const int kh = h >> 2;                 // repeat_interleave(4)
  const int q0 = qt << 7;
  const int tid  = threadIdx.x;
  const int lane = tid & 63;
  const int w = tid >> 6;
  const int rbase = lane & 15;
  const int kgrp  = (lane >> 4) << 3;
  const int r0 = (lane >> 4) << 2;
  const u16* qbase = qkv + (size_t)(b * SEQ) * 6144;

  // direct Q fragment loads (Q scale pre-folded into Wq)
  bf16x8 aq[4];
  const int qrow = q0 + w * 16 + rbase;
#pragma unroll
  for (int kc = 0; kc < 4; ++kc)
    aq[kc] = *(const bf16x8*)(qbase + (size_t)qrow * 6144 + h * HD + kc * 32 + kgrp);

  float m_r[4], l_r[4];
  f32x4 acco[8] = {};
#pragma unroll
  for (int i = 0; i < 4; ++i) { m_r[i] = -1e30f; l_r[i] = 0.f; }

  const int row_first = q0 + w * 16;
  const int nkt = (q0 >> 6) + 2;
  for (int kt = 0; kt < nkt; ++kt) {
    const int kv0 = kt << 6;
    // cooperative stage: K [64][128] and Vt [128][64] (both padded, vectorized)
#pragma unroll
    for (int p = 0; p < 2; ++p) {
      int off = p * 4096 + tid * 8;
      { int r = off >> 7, d = off & 127;
        u16x8 kvv = *(const u16x8*)(qbase + (size_t)(kv0 + r) * 6144 + 4096 + kh * HD + d);
        *(u16x8*)(Ks + r * 136 + d) = kvv; }
      { int d = off >> 6, kv = off & 63;
        u16x8 vv = *(const u16x8*)(vt + (size_t)(kh * HD + d) * 4096 + b * SEQ + kv0 + kv);
        *(u16x8*)(Vt + d * 72 + kv) = vv; }
    }
    __syncthreads();

    if (kv0 <= row_first + 15) {   // wave has at least one unmasked column
      // S = Q K^T  (this wave: 16 q-rows x 64 kv-cols)
      f32x4 accs[4] = {};
      __builtin_amdgcn_s_setprio(1);
#pragma unroll
      for (int nt = 0; nt < 4; ++nt) {
#pragma unroll
        for (int kc = 0; kc < 4; ++kc) {
          bf16x8 bk = *(const bf16x8*)&Ks[(nt * 16 + rbase) * 136 + kc * 32 + kgrp];
          accs[nt] = __builtin_amdgcn_mfma_f32_16x16x32_bf16(aq[kc], bk, accs[nt], 0, 0, 0);
        }
      }
      __builtin_amdgcn_s_setprio(0);
      // causal mask (only near-diagonal tiles)
      if (kv0 + 63 > row_first) {
#pragma unroll
        for (int nt = 0; nt < 4; ++nt)
#pragma unroll
          for (int i = 0; i < 4; ++i) {
            int row = row_first + r0 + i;
            int col = kv0 + nt * 16 + rbase;
            if (col > row) accs[nt][i] = -1e30f;
          }
      }
      // online softmax (q-row lives across the 16 lanes sharing lane>>4)
      float nm[4], al[4], rs[4];
#pragma unroll
      for (int i = 0; i < 4; ++i) {
        float mx = fmaxf(fmaxf(accs[0][i], accs[1][i]), fmaxf(accs[2][i], accs[3][i]));
        mx = fmaxf(mx, __shfl_xor(mx, 1));
        mx = fmaxf(mx, __shfl_xor(mx, 2));
        mx = fmaxf(mx, __shfl_xor(mx, 4));
        mx = fmaxf(mx, __shfl_xor(mx, 8));
        nm[i] = fmaxf(m_r[i], mx);
        al[i] = __expf(m_r[i] - nm[i]);
        m_r[i] = nm[i];
        rs[i] = 0.f;
      }
      // P = exp(S - m) -> per-wave LDS patch (C-layout -> A-frag layout)
      u16* Pw = Ps + w * 1152;
#pragma unroll
      for (int nt = 0; nt < 4; ++nt)
#pragma unroll
        for (int i = 0; i < 4; ++i) {
          float p = __expf(accs[nt][i] - nm[i]);
          rs[i] += p;
          Pw[(r0 + i) * 72 + nt * 16 + rbase] = f2bf(p);
        }
#pragma unroll
      for (int i = 0; i < 4; ++i) {
        float s = rs[i];
        s += __shfl_xor(s, 1); s += __shfl_xor(s, 2);
        s += __shfl_xor(s, 4); s += __shfl_xor(s, 8);
        l_r[i] = l_r[i] * al[i] + s;
      }
      // rescale O
#pragma unroll
      for (int n = 0; n < 8; ++n)
#pragma unroll
        for (int i = 0; i < 4; ++i) acco[n][i] *= al[i];
      // O += P V   (Vt gives contiguous B-fragments)
      bf16x8 ap[2];
#pragma unroll
      for (int kc = 0; kc < 2; ++kc)
        ap[kc] = *(const bf16x8*)&Pw[rbase * 72 + kc * 32 + kgrp];
      __builtin_amdgcn_s_setprio(1);
#pragma unroll
      for (int n = 0; n < 8; ++n) {
#pragma unroll
        for (int kc = 0; kc < 2; ++kc) {
          bf16x8 bv = *(const bf16x8*)&Vt[(n * 16 + rbase) * 72 + kc * 32 + kgrp];
          acco[n] = __builtin_amdgcn_mfma_f32_16x16x32_bf16(ap[kc], bv, acco[n], 0, 0, 0);
        }
      }
      __builtin_amdgcn_s_setprio(0);
    }
    __syncthreads();
  }

  // epilogue: O /= l, write bf16 [B*S][4096]
#pragma unroll
  for (int i = 0; i < 4; ++i) l_r[i] = 1.0f / l_r[i];
  const int orow0 = b * SEQ + q0 + w * 16 + r0;
#pragma unroll
  for (int n = 0; n < 8; ++n)
#pragma unroll
    for (int i = 0; i < 4; ++i)
      out[(size_t)(orow0 + i) * HIDDEN + h * HD + n * 16 + rbase] = f2bf(acco[n][i] * l_r[i]);
}

// ---------------- launcher ----------------
extern "C" void kernel_launch(void* const* d_in, const int* in_sizes, int n_in,
                              void* d_out, int out_size, void* d_ws, size_t ws_size,
                              hipStream_t stream) {
  (void)in_sizes; (void)n_in; (void)out_size; (void)ws_size;
  const float* x  = (const float*)d_in[0];
  const float* Wq = (const float*)d_in[1];
  const float* Wk = (const float*)d_in[2];
  const float* Wv = (const float*)d_in[3];
  const float* Wo = (const float*)d_in[4];
  float* out = (float*)d_out;

  char* ws = (char*)d_ws;
  u16* xb   = (u16*)(ws);                  // [4096][4096]   33.5 MB (dead after gemm1)
  u16* wqkv = (u16*)(ws + 33554432);       // [6144][4096]   50.3 MB
  u16* wo   = (u16*)(ws + 83886080);       // [4096][4096]   33.5 MB
  u16* qkv  = (u16*)(ws + 117440512);      // [4096][6144]   50.3 MB
  u16* attn = (u16*)(ws + 167772160);      // [4096][4096]   33.5 MB
  u16* vt   = (u16*)(ws);                  // [1024][4096]    8.4 MB, reuses xb region

  const float qscale = 0.08838834764831845f;  // 1/sqrt(128), folded into Wq

  cast_scale_k<<<2048, 256, 0, stream>>>(x,  xb,   16777216, 1.0f);
  cast_scale_k<<<2048, 256, 0, stream>>>(Wq, wqkv, 16777216, qscale);
  cast_scale_k<<<1024, 256, 0, stream>>>(Wk, wqkv + 16777216, 4194304, 1.0f);
  cast_scale_k<<<1024, 256, 0, stream>>>(Wv, wqkv + 20971520, 4194304, 1.0f);
  cast_scale_k<<<2048, 256, 0, stream>>>(Wo, wo,   16777216, 1.0f);

  // fused QKV projection: [4096,4096] x [6144,4096]^T -> [4096][6144] bf16
  gemm_bt_k<u16><<<32 * 48, 256, 0, stream>>>(xb, wqkv, qkv, 4096, 6144, 4096, 6144);

  // pre-transpose V for conflict-free attention staging
  transpose_v_k<<<1024, 256, 0, stream>>>(qkv, vt);

  // attention: B*H*(S/128) = 1024 blocks x 512 threads
  attn_k<<<1024, 512, 0, stream>>>(qkv, vt, attn);

  // O projection -> f32 output
  gemm_bt_k<float><<<32 * 32, 256, 0, stream>>>(attn, wo, out, 4096, 4096, 4096, 4096);
}